// Round 1
// baseline (1159.410 us; speedup 1.0000x reference)
//
#include <hip/hip_runtime.h>
#include <math.h>

#define FEAT_DIM 256
#define NCLS 21
#define TEMP 0.1f
#define EPSN 1e-12f

// ---------------------------------------------------------------------------
// Kernel 1: per-pixel inverse L2 norm over the channel axis.
// features layout: [D][N] (channel-major), N = H*W.
// Each thread owns 4 consecutive pixels -> float4 coalesced loads (16B/lane).
// ---------------------------------------------------------------------------
__global__ void k_norms(const float* __restrict__ feat,
                        float* __restrict__ inv_norm, int N) {
    int t  = blockIdx.x * blockDim.x + threadIdx.x;
    int n0 = t * 4;
    if (n0 >= N) return;

    float ssx = 0.f, ssy = 0.f, ssz = 0.f, ssw = 0.f;
    #pragma unroll 8
    for (int d = 0; d < FEAT_DIM; ++d) {
        float4 v = *reinterpret_cast<const float4*>(feat + (size_t)d * N + n0);
        ssx += v.x * v.x;
        ssy += v.y * v.y;
        ssz += v.z * v.z;
        ssw += v.w * v.w;
    }
    float4 r;
    r.x = 1.0f / fmaxf(sqrtf(ssx), EPSN);
    r.y = 1.0f / fmaxf(sqrtf(ssy), EPSN);
    r.z = 1.0f / fmaxf(sqrtf(ssz), EPSN);
    r.w = 1.0f / fmaxf(sqrtf(ssw), EPSN);
    *reinterpret_cast<float4*>(inv_norm + n0) = r;
}

// ---------------------------------------------------------------------------
// Kernel 2: scatter-add normalized features into per-class sums.
// LDS accumulator [21][257]: stride 257 => class c, channel d sits in bank
// (c + d) % 32, so the <=21 distinct classes hit by a wave at a fixed d land
// in 21 distinct banks (same-class lanes serialize on the same address, which
// is unavoidable for an atomic).
// ---------------------------------------------------------------------------
__global__ void k_scatter(const float* __restrict__ feat,
                          const float* __restrict__ inv_norm,
                          const int*  __restrict__ lab,
                          float* __restrict__ gsum,   // [21*256]
                          float* __restrict__ gcnt,   // [21]
                          int N) {
    __shared__ float s_acc[NCLS * 257];
    __shared__ float s_cnt[NCLS];

    for (int i = threadIdx.x; i < NCLS * 257; i += blockDim.x) s_acc[i] = 0.f;
    if (threadIdx.x < NCLS) s_cnt[threadIdx.x] = 0.f;
    __syncthreads();

    int t  = blockIdx.x * blockDim.x + threadIdx.x;
    int n0 = t * 4;
    if (n0 < N) {
        int4   L  = *reinterpret_cast<const int4*>(lab + n0);
        float4 iv = *reinterpret_cast<const float4*>(inv_norm + n0);

        atomicAdd(&s_cnt[L.x], 1.f);
        atomicAdd(&s_cnt[L.y], 1.f);
        atomicAdd(&s_cnt[L.z], 1.f);
        atomicAdd(&s_cnt[L.w], 1.f);

        const int bx = L.x * 257, by = L.y * 257, bz = L.z * 257, bw = L.w * 257;
        #pragma unroll 4
        for (int d = 0; d < FEAT_DIM; ++d) {
            float4 v = *reinterpret_cast<const float4*>(feat + (size_t)d * N + n0);
            atomicAdd(&s_acc[bx + d], v.x * iv.x);
            atomicAdd(&s_acc[by + d], v.y * iv.y);
            atomicAdd(&s_acc[bz + d], v.z * iv.z);
            atomicAdd(&s_acc[bw + d], v.w * iv.w);
        }
    }
    __syncthreads();

    for (int i = threadIdx.x; i < NCLS * FEAT_DIM; i += blockDim.x) {
        int c = i / FEAT_DIM, d = i - c * FEAT_DIM;
        float v = s_acc[c * 257 + d];
        if (v != 0.f) atomicAdd(&gsum[i], v);
    }
    if (threadIdx.x < NCLS) atomicAdd(&gcnt[threadIdx.x], s_cnt[threadIdx.x]);
}

// ---------------------------------------------------------------------------
// Kernel 3: finalize. means -> logits (21x21) -> masked contrastive loss.
// Single block of 256 threads; everything is tiny.
// ---------------------------------------------------------------------------
__global__ void k_final(const float* __restrict__ gsum,
                        const float* __restrict__ gcnt,
                        const float* __restrict__ proto,  // [21][256]
                        float* __restrict__ out) {
    __shared__ float s_mean[NCLS * 257];   // padded: bank (c+d)%32
    __shared__ float s_icnt[NCLS];
    __shared__ float s_log[NCLS * NCLS];
    __shared__ float s_term[NCLS];

    if (threadIdx.x < NCLS)
        s_icnt[threadIdx.x] = 1.0f / fmaxf(gcnt[threadIdx.x], 1.0f);
    __syncthreads();

    for (int i = threadIdx.x; i < NCLS * FEAT_DIM; i += blockDim.x) {
        int c = i / FEAT_DIM, d = i - c * FEAT_DIM;
        s_mean[c * 257 + d] = gsum[i] * s_icnt[c];
    }
    __syncthreads();

    for (int p = threadIdx.x; p < NCLS * NCLS; p += blockDim.x) {
        int c = p / NCLS, j = p - c * NCLS;
        float acc = 0.f;
        #pragma unroll 8
        for (int d = 0; d < FEAT_DIM; ++d)
            acc += s_mean[c * 257 + d] * proto[j * FEAT_DIM + d];
        s_log[p] = acc / TEMP;
    }
    __syncthreads();

    if (threadIdx.x >= 1 && threadIdx.x < NCLS) {
        int c = threadIdx.x;
        float m = -INFINITY;
        for (int j = 0; j < NCLS; ++j) m = fmaxf(m, s_log[c * NCLS + j]);
        float den = 0.f;
        for (int j = 1; j < NCLS; ++j) den += expf(s_log[c * NCLS + j] - m);
        s_term[c] = logf(den) - (s_log[c * NCLS + c] - m);
    }
    __syncthreads();

    if (threadIdx.x == 0) {
        float acc = 0.f;
        for (int c = 1; c < NCLS; ++c) acc += s_term[c];
        out[0] = acc / (float)(NCLS - 1);
    }
}

// ---------------------------------------------------------------------------
extern "C" void kernel_launch(void* const* d_in, const int* in_sizes, int n_in,
                              void* d_out, int out_size, void* d_ws, size_t ws_size,
                              hipStream_t stream) {
    const float* feat  = (const float*)d_in[0];
    const float* proto = (const float*)d_in[1];
    // d_in[2] ("outputs") is unused by the reference.
    const int*   lab   = (const int*)d_in[3];

    const int N = in_sizes[3];            // H*W = 589824
    // workspace layout
    float* inv_norm = (float*)d_ws;               // N floats
    float* gsum     = inv_norm + N;               // 21*256 floats
    float* gcnt     = gsum + NCLS * FEAT_DIM;     // 21 floats

    hipMemsetAsync(gsum, 0, (NCLS * FEAT_DIM + NCLS) * sizeof(float), stream);

    const int threads = 256;
    const int nthr    = (N + 3) / 4;              // one thread per 4 pixels
    const int blocks  = (nthr + threads - 1) / threads;   // 576 for N=589824

    k_norms  <<<blocks, threads, 0, stream>>>(feat, inv_norm, N);
    k_scatter<<<blocks, threads, 0, stream>>>(feat, inv_norm, lab, gsum, gcnt, N);
    k_final  <<<1, threads, 0, stream>>>(gsum, gcnt, proto, (float*)d_out);
}

// Round 2
// 521.565 us; speedup vs baseline: 2.2229x; 2.2229x over previous
//
#include <hip/hip_runtime.h>
#include <math.h>

#define FEAT_DIM 256
#define NCLS 21
#define TEMP 0.1f
#define TPX 64              // pixels per tile
#define NTHREADS 512        // 8 waves
#define NWAVES 8

// ---------------------------------------------------------------------------
// Async global->LDS DMA, 4B per lane. Dest must be wave-uniform (lane*4 is
// implicit); per-lane scatter is carried on the GLOBAL address (pre-swizzled
// source pattern, guide §5 / rule 21).
// ---------------------------------------------------------------------------
__device__ __forceinline__ void dma4(const float* g, float* l) {
    __builtin_amdgcn_global_load_lds(
        (const __attribute__((address_space(1))) void*)g,
        (__attribute__((address_space(3))) void*)l, 4, 0, 0);
}

// Stage tile tt (64 px x 256 ch) into dst. Wave `wid` stages rows
// [wid*32, wid*32+32). LDS slot j of row d holds pixel (j ^ (d&31)):
// source carries the swizzle, dest stays linear. This makes every later
// ds_read 2-way bank-aliased (free) instead of 32-way.
__device__ __forceinline__ void stage_tile(const float* __restrict__ feat,
                                           size_t N, int tt, float* dst,
                                           int wid, int lane) {
    const size_t px0 = (size_t)tt * TPX;
    #pragma unroll
    for (int r = 0; r < 32; ++r) {
        const int d = wid * 32 + r;
        const float* src = feat + (size_t)d * N + px0 + (size_t)(lane ^ (d & 31));
        dma4(src, dst + d * TPX);
    }
}

// ---------------------------------------------------------------------------
// Fused: per-pixel L2 norm + label-sorted per-class accumulation.
// One HBM read of features total.
// ---------------------------------------------------------------------------
__global__ __launch_bounds__(NTHREADS, 1)
void k_fused(const float* __restrict__ feat, const int* __restrict__ lab,
             float* __restrict__ gsum, float* __restrict__ gcnt, int N) {
    __shared__ float s_feat[2][FEAT_DIM * TPX];   // 128 KB double buffer
    __shared__ float s_sum[NCLS * FEAT_DIM];      // 21.5 KB block-local result
    __shared__ float s_ssp[NWAVES][TPX];          // norm partials
    __shared__ float s_iv[TPX];
    __shared__ int   s_lab[TPX];
    __shared__ int   s_order[TPX];                // pixel indices sorted by class
    __shared__ int   s_cbase[NCLS + 1];           // class segment starts (cumulative)
    __shared__ int   s_ccount[NCLS];
    __shared__ float s_cnt[NCLS];

    const int tid = threadIdx.x, lane = tid & 63, wid = tid >> 6;
    const int ntiles = N / TPX;
    const int stride = gridDim.x;

    for (int i = tid; i < NCLS * FEAT_DIM; i += NTHREADS) s_sum[i] = 0.f;
    if (tid < NCLS) s_cnt[tid] = 0.f;
    __syncthreads();

    int tt = blockIdx.x;
    if (tt < ntiles) {
        int buf = 0;
        stage_tile(feat, N, tt, s_feat[0], wid, lane);
        int labreg = (wid == 0) ? lab[(size_t)tt * TPX + lane] : 0;

        for (; tt < ntiles; tt += stride) {
            const int nxt = tt + stride;
            // publish this tile's labels (forces wave0's labreg vmcnt wait,
            // which also drains its own prior-tile DMAs — harmless)
            if (wid == 0) s_lab[lane] = labreg;
            if (nxt < ntiles) {
                stage_tile(feat, N, nxt, s_feat[buf ^ 1], wid, lane);
                if (wid == 0) labreg = lab[(size_t)nxt * TPX + lane];
                // keep the 32 new DMAs in flight; wait only for the previous
                // tile's 32 (counted vmcnt — never drain to 0 in steady state)
                asm volatile("s_waitcnt vmcnt(32) lgkmcnt(0)" ::: "memory");
            } else {
                asm volatile("s_waitcnt vmcnt(0) lgkmcnt(0)" ::: "memory");
            }
            __builtin_amdgcn_s_barrier();

            // ---- pass 1: squared-norm partials (px = lane, 32 rows/wave)
            {
                const float* fb = s_feat[buf];
                float ss = 0.f;
                #pragma unroll 8
                for (int k = 0; k < 32; ++k) {
                    const int d = wid * 32 + k;
                    const float v = fb[d * TPX + (lane ^ (d & 31))];
                    ss = fmaf(v, v, ss);
                }
                s_ssp[wid][lane] = ss;
            }
            asm volatile("s_waitcnt lgkmcnt(0)" ::: "memory");
            __builtin_amdgcn_s_barrier();

            // ---- wave1: combine partials -> inverse norms; wave0: class sort
            if (wid == 1) {
                float ss = 0.f;
                #pragma unroll
                for (int q = 0; q < NWAVES; ++q) ss += s_ssp[q][lane];
                s_iv[lane] = 1.0f / fmaxf(sqrtf(ss), 1e-12f);
            }
            if (wid == 0) {
                const int myl = s_lab[lane];
                int base = 0;
                for (int c = 0; c < NCLS; ++c) {
                    const unsigned long long m = __ballot(myl == c);
                    const int cnt = __popcll(m);
                    if (lane == 0) { s_cbase[c] = base; s_ccount[c] = cnt; }
                    if (myl == c) {
                        const int rank = __popcll(m & ((1ull << lane) - 1ull));
                        s_order[base + rank] = lane;
                    }
                    base += cnt;
                }
                if (lane == 0) s_cbase[NCLS] = base;   // == 64
            }
            asm volatile("s_waitcnt lgkmcnt(0)" ::: "memory");
            __builtin_amdgcn_s_barrier();

            // ---- pass 2: label-sorted accumulation. Lane owns channel row
            // d = 64*(wid&3)+lane; wave covers order-window of 32 pixels.
            // 1 ds_read + 1 fma per element; flush only on class change.
            {
                const float* fb = s_feat[buf];
                const int d = 64 * (wid & 3) + lane;
                const int i0 = (wid >> 2) * 32, i1 = i0 + 32;
                int c = 0;
                while (s_cbase[c + 1] <= i0) ++c;
                int cend = s_cbase[c + 1];
                float acc = 0.f;
                for (int i = i0; i < i1; ++i) {
                    if (i >= cend) {
                        if (acc != 0.f) atomicAdd(&s_sum[c * FEAT_DIM + d], acc);
                        acc = 0.f;
                        do { ++c; } while (s_cbase[c + 1] <= i);
                        cend = s_cbase[c + 1];
                    }
                    const int px = s_order[i];
                    const float w = fb[d * TPX + (px ^ (d & 31))];
                    acc = fmaf(w, s_iv[px], acc);
                }
                if (acc != 0.f) atomicAdd(&s_sum[c * FEAT_DIM + d], acc);
            }
            if (tid < NCLS) s_cnt[tid] += (float)s_ccount[tid];
            // end barrier: next iter's DMAs overwrite buf[nxt&1] == this buf^1?
            // No — they overwrite buf (two iters later target); this barrier
            // guarantees all waves finished reading s_feat[buf] / s_iv / s_order
            // before anyone issues writes that could touch them.
            asm volatile("s_waitcnt lgkmcnt(0)" ::: "memory");
            __builtin_amdgcn_s_barrier();
            buf ^= 1;
        }
    }

    __syncthreads();
    for (int i = tid; i < NCLS * FEAT_DIM; i += NTHREADS) {
        const float v = s_sum[i];
        if (v != 0.f) atomicAdd(&gsum[i], v);
    }
    if (tid < NCLS) atomicAdd(&gcnt[tid], s_cnt[tid]);
}

// ---------------------------------------------------------------------------
// Finalize: means -> 21x21 logits -> masked contrastive loss (tiny, 1 block).
// ---------------------------------------------------------------------------
__global__ void k_final(const float* __restrict__ gsum,
                        const float* __restrict__ gcnt,
                        const float* __restrict__ proto,
                        float* __restrict__ out) {
    __shared__ float s_mean[NCLS * 257];
    __shared__ float s_icnt[NCLS];
    __shared__ float s_log[NCLS * NCLS];
    __shared__ float s_term[NCLS];

    if (threadIdx.x < NCLS)
        s_icnt[threadIdx.x] = 1.0f / fmaxf(gcnt[threadIdx.x], 1.0f);
    __syncthreads();

    for (int i = threadIdx.x; i < NCLS * FEAT_DIM; i += blockDim.x) {
        const int c = i / FEAT_DIM, d = i - c * FEAT_DIM;
        s_mean[c * 257 + d] = gsum[i] * s_icnt[c];
    }
    __syncthreads();

    for (int p = threadIdx.x; p < NCLS * NCLS; p += blockDim.x) {
        const int c = p / NCLS, j = p - c * NCLS;
        float acc = 0.f;
        #pragma unroll 8
        for (int d = 0; d < FEAT_DIM; ++d)
            acc += s_mean[c * 257 + d] * proto[j * FEAT_DIM + d];
        s_log[p] = acc / TEMP;
    }
    __syncthreads();

    if (threadIdx.x >= 1 && threadIdx.x < NCLS) {
        const int c = threadIdx.x;
        float m = -INFINITY;
        for (int j = 0; j < NCLS; ++j) m = fmaxf(m, s_log[c * NCLS + j]);
        float den = 0.f;
        for (int j = 1; j < NCLS; ++j) den += expf(s_log[c * NCLS + j] - m);
        s_term[c] = logf(den) - (s_log[c * NCLS + c] - m);
    }
    __syncthreads();

    if (threadIdx.x == 0) {
        float acc = 0.f;
        for (int c = 1; c < NCLS; ++c) acc += s_term[c];
        out[0] = acc / (float)(NCLS - 1);
    }
}

// ---------------------------------------------------------------------------
extern "C" void kernel_launch(void* const* d_in, const int* in_sizes, int n_in,
                              void* d_out, int out_size, void* d_ws, size_t ws_size,
                              hipStream_t stream) {
    const float* feat  = (const float*)d_in[0];
    const float* proto = (const float*)d_in[1];
    const int*   lab   = (const int*)d_in[3];     // d_in[2] "outputs" unused

    const int N = in_sizes[3];                    // 589824 = 9216 * 64

    float* gsum = (float*)d_ws;                   // [21*256]
    float* gcnt = gsum + NCLS * FEAT_DIM;         // [21]
    hipMemsetAsync(gsum, 0, (NCLS * FEAT_DIM + NCLS) * sizeof(float), stream);

    k_fused<<<256, NTHREADS, 0, stream>>>(feat, lab, gsum, gcnt, N);
    k_final<<<1, 256, 0, stream>>>(gsum, gcnt, proto, (float*)d_out);
}

// Round 3
// 497.052 us; speedup vs baseline: 2.3326x; 1.0493x over previous
//
#include <hip/hip_runtime.h>
#include <math.h>

#define FEAT_DIM 256
#define NCLS 21
#define TEMP 0.1f
#define TPX 64              // pixels per tile
#define NTHREADS 512        // 8 waves
#define NWAVES 8

// ---------------------------------------------------------------------------
// Async global->LDS DMA, 4B per lane. LDS dest is wave-uniform (+lane*4
// implicit); the per-lane swizzle rides on the GLOBAL address (rule 21).
// ---------------------------------------------------------------------------
__device__ __forceinline__ void dma4(const float* g, float* l) {
    __builtin_amdgcn_global_load_lds(
        (const __attribute__((address_space(1))) void*)g,
        (__attribute__((address_space(3))) void*)l, 4, 0, 0);
}

// Stage tile tt: wave wid stages rows [wid*32, wid*32+32).
// LDS slot j of row d holds pixel (j ^ ((d>>1)&31)):
//  - pass1 reads (d uniform/instr): lane^const permutation -> 2-way, free
//  - pass2 reads (px uniform, d per-lane): bank = (px ^ (lane>>1))%32 -> 2-way
__device__ __forceinline__ void stage_tile(const float* __restrict__ feat,
                                           size_t N, int tt, float* dst,
                                           int wid, int lane) {
    const size_t px0 = (size_t)tt * TPX;
    #pragma unroll
    for (int r = 0; r < 32; ++r) {
        const int d  = wid * 32 + r;
        const int sw = (d >> 1) & 31;
        dma4(feat + (size_t)d * N + px0 + (size_t)(lane ^ sw), dst + d * TPX);
    }
}

// ---------------------------------------------------------------------------
// Fused: per-pixel L2 norm + label-sorted per-class accumulation.
// One HBM read of features; no per-element atomics; no dependent LDS chains.
// ---------------------------------------------------------------------------
__global__ __launch_bounds__(NTHREADS, 1)
void k_fused(const float* __restrict__ feat, const int* __restrict__ lab,
             float* __restrict__ gsum, float* __restrict__ gcnt, int N) {
    __shared__ float s_feat[2][FEAT_DIM * TPX];   // 128 KB double buffer
    __shared__ float s_sum[NCLS * FEAT_DIM];      // block-local class sums
    __shared__ float s_ssp[NWAVES][TPX];          // norm partials
    __shared__ float s_iv[TPX];
    __shared__ int   s_lab[TPX];
    __shared__ int   s_order[TPX];                // sorted j -> pixel
    __shared__ int   s_cls[TPX];                  // sorted j -> class

    const int tid = threadIdx.x, lane = tid & 63, wid = tid >> 6;
    const int ntiles = N / TPX;
    const int stride = gridDim.x;

    float cntf = 0.f;                             // wave0 lane c: class-c count

    for (int i = tid; i < NCLS * FEAT_DIM; i += NTHREADS) s_sum[i] = 0.f;
    __syncthreads();

    int tt = blockIdx.x;
    if (tt < ntiles) {
        int buf = 0;
        int labreg = 0;
        // prologue: label load FIRST (so its consume-wait is vmcnt(32),
        // leaving the 32 feature DMAs in flight), then stage tile 0.
        if (wid == 0) labreg = lab[(size_t)tt * TPX + lane];
        stage_tile(feat, N, tt, s_feat[0], wid, lane);

        for (; tt < ntiles; tt += stride) {
            const int nxt = tt + stride;
            // publish labels (compiler inserts minimal vmcnt for labreg)
            if (wid == 0) s_lab[lane] = labreg;
            if (nxt < ntiles) {
                if (wid == 0) labreg = lab[(size_t)nxt * TPX + lane];
                stage_tile(feat, N, nxt, s_feat[buf ^ 1], wid, lane);
                // wait current tile's 32 DMAs; keep next tile's in flight.
                // wave0's queue: [32 feat][lab'][32 feat'] -> 33 newer entries.
                if (wid == 0)
                    asm volatile("s_waitcnt vmcnt(33) lgkmcnt(0)" ::: "memory");
                else
                    asm volatile("s_waitcnt vmcnt(32) lgkmcnt(0)" ::: "memory");
            } else {
                asm volatile("s_waitcnt vmcnt(0) lgkmcnt(0)" ::: "memory");
            }
            __builtin_amdgcn_s_barrier();

            const float* fb = s_feat[buf];

            // ---- pass 1: squared-norm partials (lane = pixel, 32 rows/wave)
            {
                float ss = 0.f;
                #pragma unroll
                for (int k = 0; k < 32; ++k) {
                    const int d  = wid * 32 + k;
                    const int sw = (d >> 1) & 31;
                    const float v = fb[d * TPX + (lane ^ sw)];
                    ss = fmaf(v, v, ss);
                }
                s_ssp[wid][lane] = ss;
            }
            asm volatile("s_waitcnt lgkmcnt(0)" ::: "memory");
            __builtin_amdgcn_s_barrier();

            // ---- phase B: wave1 combines norms; wave0 class-sorts pixels
            if (wid == 1) {
                float ss = 0.f;
                #pragma unroll
                for (int q = 0; q < NWAVES; ++q) ss += s_ssp[q][lane];
                s_iv[lane] = 1.0f / fmaxf(sqrtf(ss), 1e-12f);
            }
            if (wid == 0) {
                const int myl = s_lab[lane];
                int base = 0;
                for (int c = 0; c < NCLS; ++c) {
                    const unsigned long long m = __ballot(myl == c);
                    const int cnt = __popcll(m);
                    if (myl == c) {
                        const int rank = __popcll(m & ((1ull << lane) - 1ull));
                        s_order[base + rank] = lane;
                        s_cls[base + rank]   = c;
                    }
                    if (lane == c) cntf += (float)cnt;   // register, no LDS rmw
                    base += cnt;
                }
            }
            asm volatile("s_waitcnt lgkmcnt(0)" ::: "memory");
            __builtin_amdgcn_s_barrier();

            // ---- pass 2: lane owns channel d; window of 32 sorted pixels.
            // All metadata hoisted to registers; per-pixel px/iv/cls come from
            // readlane (unrolled shfl) -> zero per-iteration LDS latency.
            {
                const int d  = 64 * (wid & 3) + lane;
                const int j0 = (wid >> 2) * 32;
                const int sw = (lane >> 1) & 31;      // == (d>>1)&31

                const int   pxr = s_order[j0 + (lane & 31)];
                const int   clr = s_cls[j0 + (lane & 31)];
                const float ivr = s_iv[pxr];

                float v[32];
                #pragma unroll
                for (int k = 0; k < 32; ++k) {
                    const int px = __shfl(pxr, k);
                    v[k] = fb[d * TPX + (px ^ sw)];   // independent, batched
                }

                float acc = 0.f;
                int c = __builtin_amdgcn_readfirstlane(__shfl(clr, 0));
                #pragma unroll
                for (int k = 0; k < 32; ++k) {
                    const int ck = __builtin_amdgcn_readfirstlane(__shfl(clr, k));
                    if (ck != c) {                     // scalar branch
                        atomicAdd(&s_sum[c * FEAT_DIM + d], acc);
                        acc = 0.f; c = ck;
                    }
                    const float ivk = __shfl(ivr, k);
                    acc = fmaf(v[k], ivk, acc);
                }
                atomicAdd(&s_sum[c * FEAT_DIM + d], acc);
            }
            asm volatile("s_waitcnt lgkmcnt(0)" ::: "memory");
            __builtin_amdgcn_s_barrier();   // protect fb before next overwrite
            buf ^= 1;
        }
    }

    __syncthreads();
    for (int i = tid; i < NCLS * FEAT_DIM; i += NTHREADS) {
        const float v = s_sum[i];
        if (v != 0.f) atomicAdd(&gsum[i], v);
    }
    if (wid == 0 && lane < NCLS) atomicAdd(&gcnt[lane], cntf);
}

// ---------------------------------------------------------------------------
// Finalize: means -> 21x21 logits -> masked contrastive loss (tiny, 1 block).
// ---------------------------------------------------------------------------
__global__ void k_final(const float* __restrict__ gsum,
                        const float* __restrict__ gcnt,
                        const float* __restrict__ proto,
                        float* __restrict__ out) {
    __shared__ float s_mean[NCLS * 257];
    __shared__ float s_icnt[NCLS];
    __shared__ float s_log[NCLS * NCLS];
    __shared__ float s_term[NCLS];

    if (threadIdx.x < NCLS)
        s_icnt[threadIdx.x] = 1.0f / fmaxf(gcnt[threadIdx.x], 1.0f);
    __syncthreads();

    for (int i = threadIdx.x; i < NCLS * FEAT_DIM; i += blockDim.x) {
        const int c = i / FEAT_DIM, d = i - c * FEAT_DIM;
        s_mean[c * 257 + d] = gsum[i] * s_icnt[c];
    }
    __syncthreads();

    for (int p = threadIdx.x; p < NCLS * NCLS; p += blockDim.x) {
        const int c = p / NCLS, j = p - c * NCLS;
        float acc = 0.f;
        #pragma unroll 8
        for (int d = 0; d < FEAT_DIM; ++d)
            acc += s_mean[c * 257 + d] * proto[j * FEAT_DIM + d];
        s_log[p] = acc / TEMP;
    }
    __syncthreads();

    if (threadIdx.x >= 1 && threadIdx.x < NCLS) {
        const int c = threadIdx.x;
        float m = -INFINITY;
        for (int j = 0; j < NCLS; ++j) m = fmaxf(m, s_log[c * NCLS + j]);
        float den = 0.f;
        for (int j = 1; j < NCLS; ++j) den += expf(s_log[c * NCLS + j] - m);
        s_term[c] = logf(den) - (s_log[c * NCLS + c] - m);
    }
    __syncthreads();

    if (threadIdx.x == 0) {
        float acc = 0.f;
        for (int c = 1; c < NCLS; ++c) acc += s_term[c];
        out[0] = acc / (float)(NCLS - 1);
    }
}

// ---------------------------------------------------------------------------
extern "C" void kernel_launch(void* const* d_in, const int* in_sizes, int n_in,
                              void* d_out, int out_size, void* d_ws, size_t ws_size,
                              hipStream_t stream) {
    const float* feat  = (const float*)d_in[0];
    const float* proto = (const float*)d_in[1];
    const int*   lab   = (const int*)d_in[3];     // d_in[2] "outputs" unused

    const int N = in_sizes[3];                    // 589824 = 9216 * 64

    float* gsum = (float*)d_ws;                   // [21*256]
    float* gcnt = gsum + NCLS * FEAT_DIM;         // [21]
    hipMemsetAsync(gsum, 0, (NCLS * FEAT_DIM + NCLS) * sizeof(float), stream);

    k_fused<<<256, NTHREADS, 0, stream>>>(feat, lab, gsum, gcnt, N);
    k_final<<<1, 256, 0, stream>>>(gsum, gcnt, proto, (float*)d_out);
}